// Round 6
// baseline (58.174 us; speedup 1.0000x reference)
//
#include <hip/hip_runtime.h>

#define BTOT 4096
#define G 4               // batch items per block (one per wave)
#define NC 16
#define WIN 247
#define NBLK (BTOT / G)   // 1024 blocks

__device__ __forceinline__ unsigned bf16rne(float f) {
    unsigned u = __float_as_uint(f);
    return (u + 0x7fffu + ((u >> 16) & 1u)) >> 16;
}

// ---------------- Kernel 1: conv (float4 streaming, bf16 W) + nonlinearity + projections ----------------
__global__ __launch_bounds__(256, 2) void k_main(
    const float* __restrict__ x,
    const float* __restrict__ Wr, const float* __restrict__ Wi,
    const float* __restrict__ Wnl, const float* __restrict__ Wc,
    const float* __restrict__ Wor, const float* __restrict__ Woi,
    float* __restrict__ out, float* __restrict__ ws)
{
    // WL2[(k+9)*8 + cp] = bf16x4 {Wr[2cp][k], Wi[2cp][k], Wr[2cp+1][k], Wi[2cp+1][k]}, 0 outside [0,247)
    __shared__ uint2 WL2[265 * 8];      // 16960 B
    __shared__ float Mlds[4 * 256];     // 4096 B: M0r | M0i | M1r | M1i, zero-diagonal 16x16
    __shared__ float WoS[2 * 160];      // 1280 B
    __shared__ float WcS[4];

    const int tid   = threadIdx.x;
    const int lane  = tid & 63;
    const int b_loc = tid >> 6;         // wave = one batch item
    const int cp    = lane & 7;         // channel pair: c0=2cp, c1=2cp+1
    const int ns    = lane >> 3;        // n-segment 0..7
    const int n0    = ns * 32;
    const int b0    = blockIdx.x * G;

    // ---- stage packed W table (zero-padded) ----
    for (int idx = tid; idx < 265 * 8; idx += 256) {
        int m = idx >> 3, cc = idx & 7;
        int k = m - 9;
        uint2 p = make_uint2(0u, 0u);
        if (k >= 0 && k < WIN) {
            p.x = bf16rne(Wr[(2 * cc) * WIN + k])     | (bf16rne(Wi[(2 * cc) * WIN + k]) << 16);
            p.y = bf16rne(Wr[(2 * cc + 1) * WIN + k]) | (bf16rne(Wi[(2 * cc + 1) * WIN + k]) << 16);
        }
        WL2[idx] = p;
    }
    // ---- build zero-diagonal neighbor matrices from W_nl ----
    for (int idx = tid; idx < 1024; idx += 256) {
        int m  = idx >> 8;          // 0..3 : o = m>>1, part = m&1
        int cc = (idx >> 4) & 15;
        int j  = idx & 15;
        float v = 0.f;
        if (j != cc) {
            int jj = j - (j > cc);
            v = Wnl[cc * 60 + (m >> 1) * 30 + (m & 1) * 15 + jj];
        }
        Mlds[idx] = v;
    }
    if (tid < 160) { WoS[tid] = Wor[tid]; WoS[160 + tid] = Woi[tid]; }
    if (tid < 4) WcS[tid] = Wc[tid];
    __syncthreads();

    // x[b, n, c, ri] as float4: element (b, n, cp) at xp[n*8], spans channels 2cp, 2cp+1
    const float4* xp = (const float4*)x + (size_t)(b0 + b_loc) * 2048 + cp;
    // W window source: Wb[t*8] = tap k = n0 + t - 9  (t in [0,41))
    const uint2* Wb = WL2 + n0 * 8 + cp;

    float ar0[10], ai0[10], ar1[10], ai1[10];
    float4 win[10], xr[4];
    uint2 wpre;
    #pragma unroll
    for (int w = 0; w < 10; ++w) { ar0[w] = 0.f; ai0[w] = 0.f; ar1[w] = 0.f; ai1[w] = 0.f; }

    #pragma unroll
    for (int t = 0; t < 10; ++t) {
        uint2 u = Wb[t * 8];
        win[t].x = __uint_as_float(u.x << 16);
        win[t].y = __uint_as_float(u.x & 0xffff0000u);
        win[t].z = __uint_as_float(u.y << 16);
        win[t].w = __uint_as_float(u.y & 0xffff0000u);
    }
    wpre = Wb[10 * 8];
    #pragma unroll
    for (int j = 0; j < 4; ++j) xr[j] = xp[(n0 + j) * 8];

    // ---- conv: 32 n-steps; x prefetch depth 4; W prefetch depth 2 (wpre -> win) ----
    #pragma unroll
    for (int i = 0; i < 32; ++i) {
        float4 xv = xr[i & 3];
        if (i < 28) xr[i & 3] = xp[(n0 + i + 4) * 8];
        #pragma unroll
        for (int w = 0; w < 10; ++w) {
            float4 t4 = win[(i + 9 - w) % 10];      // tap k = n0 + i - w
            ar0[w] = fmaf(xv.x, t4.x, ar0[w]);
            ai0[w] = fmaf(xv.y, t4.y, ai0[w]);
            ar1[w] = fmaf(xv.z, t4.z, ar1[w]);
            ai1[w] = fmaf(xv.w, t4.w, ai1[w]);
        }
        {   // rotate in wpre (becomes tap k = n0 + i + 1)
            float4 wf;
            wf.x = __uint_as_float(wpre.x << 16);
            wf.y = __uint_as_float(wpre.x & 0xffff0000u);
            wf.z = __uint_as_float(wpre.y << 16);
            wf.w = __uint_as_float(wpre.y & 0xffff0000u);
            win[i % 10] = wf;
        }
        if (i < 30) wpre = Wb[(i + 11) * 8];
    }

    // ---- reduce over ns (lane bits 3,4,5) ----
    #pragma unroll
    for (int w = 0; w < 10; ++w) {
        ar0[w] += __shfl_xor(ar0[w], 8);  ar0[w] += __shfl_xor(ar0[w], 16);  ar0[w] += __shfl_xor(ar0[w], 32);
        ai0[w] += __shfl_xor(ai0[w], 8);  ai0[w] += __shfl_xor(ai0[w], 16);  ai0[w] += __shfl_xor(ai0[w], 32);
        ar1[w] += __shfl_xor(ar1[w], 8);  ar1[w] += __shfl_xor(ar1[w], 16);  ar1[w] += __shfl_xor(ar1[w], 32);
        ai1[w] += __shfl_xor(ai1[w], 8);  ai1[w] += __shfl_xor(ai1[w], 16);  ai1[w] += __shfl_xor(ai1[w], 32);
    }

    __syncthreads();                    // conv reads of WL2 done -> safe to alias
    float* S    = (float*)WL2;
    float* fbuf = S;                    // [b][c][{r,i}][w] : G*320 = 1280 f
    float* crS  = S + 1280;             // 640 f
    float* ciS  = S + 1920;             // 640 f
    float* red  = S + 2560;             // 64 f
    float* redq = S + 2624;             // 64 f

    // ---- amp nonlinearity (values fully reduced in-register) ----
    if (lane < 8) {
        #pragma unroll
        for (int w = 0; w < 10; ++w) {
            float fr0 = ar0[w], fi0 = ai0[w];
            float a0  = fr0 * fr0 + fi0 * fi0;
            fbuf[b_loc * 320 + (2 * cp) * 20 + w]      = a0 * fr0;
            fbuf[b_loc * 320 + (2 * cp) * 20 + 10 + w] = a0 * fi0;
            float fr1 = ar1[w], fi1 = ai1[w];
            float a1  = fr1 * fr1 + fi1 * fi1;
            fbuf[b_loc * 320 + (2 * cp + 1) * 20 + w]      = a1 * fr1;
            fbuf[b_loc * 320 + (2 * cp + 1) * 20 + 10 + w] = a1 * fi1;
        }
    }
    __syncthreads();

    // ---- phase 3: branchless neighbor einsum + coeff + output-window weights ----
    const float* M0r = Mlds;
    const float* M0i = Mlds + 256;
    const float* M1r = Mlds + 512;
    const float* M1i = Mlds + 768;
    for (int idx = tid; idx < G * 160; idx += 256) {
        int bb = idx / 160; int r = idx - bb * 160;
        int cc = r / 10;    int w = r - cc * 10;
        const float* f3 = fbuf + bb * 320;
        float s0 = 0.f, s1 = 0.f;
        #pragma unroll
        for (int j = 0; j < NC; ++j) {
            float f3r = f3[j * 20 + w];
            float f3i = f3[j * 20 + 10 + w];
            s0 = fmaf(f3r, M0r[cc * 16 + j], fmaf(f3i, M0i[cc * 16 + j], s0));
            s1 = fmaf(f3r, M1r[cc * 16 + j], fmaf(f3i, M1i[cc * 16 + j], s1));
        }
        float p0 = s0 * WcS[0] + s1 * WcS[1];
        float p1 = s0 * WcS[2] + s1 * WcS[3];
        crS[idx] = p0 * WoS[cc * 10 + w];
        ciS[idx] = p1 * WoS[160 + cc * 10 + w];
    }
    __syncthreads();

    // ---- phase 4: sum over w, write out + BN partials ----
    if (tid < G * NC) {
        int bb = tid >> 4; int cc = tid & 15;
        float orr = 0.f, oii = 0.f;
        #pragma unroll
        for (int w = 0; w < 10; ++w) {
            orr += crS[bb * 160 + cc * 10 + w];
            oii += ciS[bb * 160 + cc * 10 + w];
        }
        size_t o = ((size_t)(b0 + bb) * NC + cc) * 2;
        out[o]     = orr;
        out[o + 1] = oii;
        red[tid]  = orr + oii;
        redq[tid] = orr * orr + oii * oii;
    }
    __syncthreads();
    if (tid < NC) {
        float s = 0.f, qq = 0.f;
        #pragma unroll
        for (int bb = 0; bb < G; ++bb) { s += red[bb * 16 + tid]; qq += redq[bb * 16 + tid]; }
        ws[(tid * NBLK + blockIdx.x) * 2]     = s;
        ws[(tid * NBLK + blockIdx.x) * 2 + 1] = qq;
    }
}

// ---------------- Kernel 2: reduce partials -> per-channel scale/shift ----------------
__global__ __launch_bounds__(256) void k_bnstat(
    const float* __restrict__ ws_in, float* __restrict__ ws_ab,
    const float* __restrict__ gamma, const float* __restrict__ beta)
{
    const int cch = blockIdx.x;
    const int tid = threadIdx.x;
    float s = 0.f, q = 0.f;
    for (int i = tid; i < NBLK; i += 256) {
        s += ws_in[(cch * NBLK + i) * 2];
        q += ws_in[(cch * NBLK + i) * 2 + 1];
    }
    #pragma unroll
    for (int off = 32; off; off >>= 1) {
        s += __shfl_down(s, off, 64);
        q += __shfl_down(q, off, 64);
    }
    __shared__ float rs[4], rq[4];
    const int wv = tid >> 6;
    if ((tid & 63) == 0) { rs[wv] = s; rq[wv] = q; }
    __syncthreads();
    if (tid == 0) {
        s = rs[0] + rs[1] + rs[2] + rs[3];
        q = rq[0] + rq[1] + rq[2] + rq[3];
        const float inv_n = 1.f / (BTOT * 2.f);
        float mu  = s * inv_n;
        float var = q * inv_n - mu * mu;
        float sc  = gamma[cch] * rsqrtf(var + 1e-5f);
        ws_ab[cch]      = sc;
        ws_ab[16 + cch] = beta[cch] - mu * sc;
    }
}

// ---------------- Kernel 3: apply BN affine in place ----------------
__global__ __launch_bounds__(256) void k_bnapply(
    float* __restrict__ out, const float* __restrict__ ws_ab)
{
    __shared__ float A[16], Bb[16];
    const int tid = threadIdx.x;
    if (tid < 16) { A[tid] = ws_ab[tid]; Bb[tid] = ws_ab[16 + tid]; }
    __syncthreads();
    int idx = blockIdx.x * 256 + tid;
    if (idx < BTOT * NC * 2) {
        int cch = (idx >> 1) & 15;
        out[idx] = out[idx] * A[cch] + Bb[cch];
    }
}

extern "C" void kernel_launch(void* const* d_in, const int* in_sizes, int n_in,
                              void* d_out, int out_size, void* d_ws, size_t ws_size,
                              hipStream_t stream)
{
    const float* x    = (const float*)d_in[0];
    const float* Wr   = (const float*)d_in[1];
    const float* Wi   = (const float*)d_in[2];
    const float* Wnl  = (const float*)d_in[3];
    const float* Wc   = (const float*)d_in[4];
    const float* Wor  = (const float*)d_in[5];
    const float* Woi  = (const float*)d_in[6];
    const float* gam  = (const float*)d_in[7];
    const float* bet  = (const float*)d_in[8];
    float* out = (float*)d_out;
    float* ws  = (float*)d_ws;
    float* ws_ab = ws + NC * NBLK * 2;   // 32768 floats of partials, then 32 floats scale/shift

    k_main<<<NBLK, 256, 0, stream>>>(x, Wr, Wi, Wnl, Wc, Wor, Woi, out, ws);
    k_bnstat<<<NC, 256, 0, stream>>>(ws, ws_ab, gam, bet);
    k_bnapply<<<(BTOT * NC * 2 + 255) / 256, 256, 0, stream>>>(out, ws_ab);
}

// Round 7
// 50.475 us; speedup vs baseline: 1.1525x; 1.1525x over previous
//
#include <hip/hip_runtime.h>

#define BTOT 4096
#define G 4               // batch items per block (one per wave)
#define NC 16
#define WIN 247
#define NBLK (BTOT / G)   // 1024 blocks

// W table in LDS, float2 {Wr,Wi} per (tap m, channel c); m = t+9, t = global tap.
// Skew: +8 float2 per 64-m block -> ns-groups land on disjoint/2-way bank sets.
#define F2IDX(m, c) ((m) * 16 + (c) + ((m) >> 6) * 8)
#define WTSZ 4272         // F2IDX(264,15)+1

// ---------------- Kernel 1: conv (float2 streaming, depth-8) + nonlinearity + projections ----------------
__global__ __launch_bounds__(256, 4) void k_main(
    const float* __restrict__ x,
    const float* __restrict__ Wr, const float* __restrict__ Wi,
    const float* __restrict__ Wnl, const float* __restrict__ Wc,
    const float* __restrict__ Wor, const float* __restrict__ Woi,
    float* __restrict__ out, float* __restrict__ ws)
{
    __shared__ float2 WT[WTSZ];         // 34176 B
    __shared__ float Mlds[4 * 16 * 17]; // 4352 B, stride 17 (conflict-free)
    __shared__ float WoS[2 * 160];      // 1280 B
    __shared__ float WcS[4];

    const int tid  = threadIdx.x;
    const int lane = tid & 63;
    const int wv   = tid >> 6;          // wave = one batch item
    const int ns   = lane >> 4;         // n-segment 0..3 (64 n each)
    const int c    = lane & 15;         // channel
    const int n0   = ns * 64;
    const int b0   = blockIdx.x * G;

    // ---- stage W table (zero-padded, fp32) ----
    for (int idx = tid; idx < 265 * 16; idx += 256) {
        int m = idx >> 4, cc = idx & 15;
        int t = m - 9;
        float2 v = make_float2(0.f, 0.f);
        if (t >= 0 && t < WIN) { v.x = Wr[cc * WIN + t]; v.y = Wi[cc * WIN + t]; }
        WT[F2IDX(m, cc)] = v;
    }
    // ---- zero-diagonal neighbor matrices, stride 17 ----
    for (int idx = tid; idx < 1024; idx += 256) {
        int m  = idx >> 8;              // 0..3 : o = m>>1, part = m&1
        int cc = (idx >> 4) & 15;
        int j  = idx & 15;
        float v = 0.f;
        if (j != cc) {
            int jj = j - (j > cc);
            v = Wnl[cc * 60 + (m >> 1) * 30 + (m & 1) * 15 + jj];
        }
        Mlds[m * 272 + cc * 17 + j] = v;
    }
    if (tid < 160) { WoS[tid] = Wor[tid]; WoS[160 + tid] = Woi[tid]; }
    if (tid < 4) WcS[tid] = Wc[tid];
    __syncthreads();

    // x[b, n, c, ri] as float2: element (b, n, c) at xp[n*16]
    const float2* xp = (const float2*)x + (size_t)(b0 + wv) * 4096 + c;

    float accr[10], acci[10];
    float2 win[11];                     // W window, slot = local-m % 11
    float2 xr[8];                       // depth-8 x prefetch
    #pragma unroll
    for (int w = 0; w < 10; ++w) { accr[w] = 0.f; acci[w] = 0.f; }

    #pragma unroll
    for (int j = 0; j < 11; ++j) win[j] = WT[F2IDX(n0 + j, c)];
    #pragma unroll
    for (int j = 0; j < 8; ++j) xr[j] = xp[(n0 + j) * 16];

    // ---- conv: 64 n-steps; x depth-8; W read 2 iters ahead ----
    #pragma unroll
    for (int i = 0; i < 64; ++i) {
        float2 xv = xr[i & 7];
        if (i < 56) xr[i & 7] = xp[(n0 + i + 8) * 16];
        #pragma unroll
        for (int w = 0; w < 10; ++w) {
            float2 wt = win[(i + 9 - w) % 11];   // tap m_loc = i+9-w
            accr[w] = fmaf(xv.x, wt.x, accr[w]);
            acci[w] = fmaf(xv.y, wt.y, acci[w]);
        }
        if (i < 62) win[i % 11] = WT[F2IDX(n0 + 11 + i, c)];
    }

    // ---- reduce over ns (lane bits 4,5) ----
    #pragma unroll
    for (int w = 0; w < 10; ++w) {
        accr[w] += __shfl_xor(accr[w], 16);  accr[w] += __shfl_xor(accr[w], 32);
        acci[w] += __shfl_xor(acci[w], 16);  acci[w] += __shfl_xor(acci[w], 32);
    }

    __syncthreads();                    // all conv reads of WT done -> safe to alias
    float* S    = (float*)WT;
    float* fbuf = S;                    // [b][c][{r,i}][w] : G*320 = 1280 f
    float* crS  = S + 1280;             // 640 f
    float* ciS  = S + 1920;             // 640 f
    float* red  = S + 2560;             // 64 f
    float* redq = S + 2624;             // 64 f

    // ---- amp nonlinearity (fully reduced in-register) ----
    if (lane < 16) {
        #pragma unroll
        for (int w = 0; w < 10; ++w) {
            float fr = accr[w], fi = acci[w];
            float a  = fr * fr + fi * fi;
            fbuf[wv * 320 + c * 20 + w]      = a * fr;
            fbuf[wv * 320 + c * 20 + 10 + w] = a * fi;
        }
    }
    __syncthreads();

    // ---- phase 3: neighbor einsum + coeff + output-window weights ----
    const float* M0r = Mlds;
    const float* M0i = Mlds + 272;
    const float* M1r = Mlds + 544;
    const float* M1i = Mlds + 816;
    for (int idx = tid; idx < G * 160; idx += 256) {
        int bb = idx / 160; int r = idx - bb * 160;
        int cc = r / 10;    int w = r - cc * 10;
        const float* f3 = fbuf + bb * 320;
        float s0 = 0.f, s1 = 0.f;
        #pragma unroll
        for (int j = 0; j < NC; ++j) {
            float f3r = f3[j * 20 + w];
            float f3i = f3[j * 20 + 10 + w];
            s0 = fmaf(f3r, M0r[cc * 17 + j], fmaf(f3i, M0i[cc * 17 + j], s0));
            s1 = fmaf(f3r, M1r[cc * 17 + j], fmaf(f3i, M1i[cc * 17 + j], s1));
        }
        float p0 = s0 * WcS[0] + s1 * WcS[1];
        float p1 = s0 * WcS[2] + s1 * WcS[3];
        crS[idx] = p0 * WoS[cc * 10 + w];
        ciS[idx] = p1 * WoS[160 + cc * 10 + w];
    }
    __syncthreads();

    // ---- phase 4: sum over w, write out + BN partials ----
    if (tid < G * NC) {
        int bb = tid >> 4; int cc = tid & 15;
        float orr = 0.f, oii = 0.f;
        #pragma unroll
        for (int w = 0; w < 10; ++w) {
            orr += crS[bb * 160 + cc * 10 + w];
            oii += ciS[bb * 160 + cc * 10 + w];
        }
        size_t o = ((size_t)(b0 + bb) * NC + cc) * 2;
        out[o]     = orr;
        out[o + 1] = oii;
        red[tid]  = orr + oii;
        redq[tid] = orr * orr + oii * oii;
    }
    __syncthreads();
    if (tid < NC) {
        float s = 0.f, qq = 0.f;
        #pragma unroll
        for (int bb = 0; bb < G; ++bb) { s += red[bb * 16 + tid]; qq += redq[bb * 16 + tid]; }
        ws[(tid * NBLK + blockIdx.x) * 2]     = s;
        ws[(tid * NBLK + blockIdx.x) * 2 + 1] = qq;
    }
}

// ---------------- Kernel 2: reduce partials -> per-channel scale/shift ----------------
__global__ __launch_bounds__(256) void k_bnstat(
    const float* __restrict__ ws_in, float* __restrict__ ws_ab,
    const float* __restrict__ gamma, const float* __restrict__ beta)
{
    const int cch = blockIdx.x;
    const int tid = threadIdx.x;
    float s = 0.f, q = 0.f;
    for (int i = tid; i < NBLK; i += 256) {
        s += ws_in[(cch * NBLK + i) * 2];
        q += ws_in[(cch * NBLK + i) * 2 + 1];
    }
    #pragma unroll
    for (int off = 32; off; off >>= 1) {
        s += __shfl_down(s, off, 64);
        q += __shfl_down(q, off, 64);
    }
    __shared__ float rs[4], rq[4];
    const int wv = tid >> 6;
    if ((tid & 63) == 0) { rs[wv] = s; rq[wv] = q; }
    __syncthreads();
    if (tid == 0) {
        s = rs[0] + rs[1] + rs[2] + rs[3];
        q = rq[0] + rq[1] + rq[2] + rq[3];
        const float inv_n = 1.f / (BTOT * 2.f);
        float mu  = s * inv_n;
        float var = q * inv_n - mu * mu;
        float sc  = gamma[cch] * rsqrtf(var + 1e-5f);
        ws_ab[cch]      = sc;
        ws_ab[16 + cch] = beta[cch] - mu * sc;
    }
}

// ---------------- Kernel 3: apply BN affine in place ----------------
__global__ __launch_bounds__(256) void k_bnapply(
    float* __restrict__ out, const float* __restrict__ ws_ab)
{
    __shared__ float A[16], Bb[16];
    const int tid = threadIdx.x;
    if (tid < 16) { A[tid] = ws_ab[tid]; Bb[tid] = ws_ab[16 + tid]; }
    __syncthreads();
    int idx = blockIdx.x * 256 + tid;
    if (idx < BTOT * NC * 2) {
        int cch = (idx >> 1) & 15;
        out[idx] = out[idx] * A[cch] + Bb[cch];
    }
}

extern "C" void kernel_launch(void* const* d_in, const int* in_sizes, int n_in,
                              void* d_out, int out_size, void* d_ws, size_t ws_size,
                              hipStream_t stream)
{
    const float* x    = (const float*)d_in[0];
    const float* Wr   = (const float*)d_in[1];
    const float* Wi   = (const float*)d_in[2];
    const float* Wnl  = (const float*)d_in[3];
    const float* Wc   = (const float*)d_in[4];
    const float* Wor  = (const float*)d_in[5];
    const float* Woi  = (const float*)d_in[6];
    const float* gam  = (const float*)d_in[7];
    const float* bet  = (const float*)d_in[8];
    float* out = (float*)d_out;
    float* ws  = (float*)d_ws;
    float* ws_ab = ws + NC * NBLK * 2;   // 32768 floats of partials, then 32 floats scale/shift

    k_main<<<NBLK, 256, 0, stream>>>(x, Wr, Wi, Wnl, Wc, Wor, Woi, out, ws);
    k_bnstat<<<NC, 256, 0, stream>>>(ws, ws_ab, gam, bet);
    k_bnapply<<<(BTOT * NC * 2 + 255) / 256, 256, 0, stream>>>(out, ws_ab);
}